// Round 2
// baseline (425.801 us; speedup 1.0000x reference)
//
#include <hip/hip_runtime.h>

// 4096-pt FWHT per row, one block (256 thr) per row, single pass over HBM.
// FWHT = tensor product of 12 1-bit butterflies; stages commute, so the 12
// index bits are split into three groups of 4 done as register-resident
// 16-pt FWHTs:  G1={0,1,10,11}, G2={2,3,4,5}, G3={6,7,8,9}.
// This choice makes BOTH global loads and stores perfectly unit-stride
// float4 across lanes (thread t <-> float4 index t+256k), at the cost of a
// third LDS transpose. LDS swizzles chosen so every b128 access is
// conflict-free and every scalar b32 access is <=2 lanes/bank (free).

__device__ __forceinline__ void fwht16(float v[16]) {
#pragma unroll
    for (int s = 1; s < 16; s <<= 1) {
#pragma unroll
        for (int i = 0; i < 16; ++i) {
            if ((i & s) == 0) {
                float a = v[i], b = v[i | s];
                v[i]     = a + b;
                v[i | s] = a - b;
            }
        }
    }
}

__global__ __launch_bounds__(256) void fwht4096_kernel(const float* __restrict__ x,
                                                       float* __restrict__ out) {
    // e-ordered buffers (T1, T3): word addr = 4*g(e>>2) + (e&3),
    //   g(u) = u + (u>>4) + 2*(u>>8), max word = 4*1092+3 = 4371.
    // thread-major buffer (T2): word addr = 20*t + j, max = 5115.
    __shared__ float lds[5120];

    const int t = threadIdx.x;                 // 0..255
    const size_t base = (size_t)blockIdx.x * 4096;
    float v[16];

    // ---- Load: reg j=4k+c holds e = 4t + 1024k + c  (c=e[1:0], k=e[11:10]) ----
    const float4* px = (const float4*)(x + base);
#pragma unroll
    for (int k = 0; k < 4; ++k) {
        float4 q = px[t + 256 * k];            // unit-stride across lanes
        v[4*k+0] = q.x; v[4*k+1] = q.y; v[4*k+2] = q.z; v[4*k+3] = q.w;
    }

    fwht16(v);                                  // bits {0,1,10,11}

    // ---- T1 write (b128): u = t+256k -> g = t + (t>>4) + 274k ----
    {
        const int gw = t + (t >> 4);
#pragma unroll
        for (int k = 0; k < 4; ++k) {
            *(float4*)&lds[4 * (gw + 274 * k)] =
                make_float4(v[4*k], v[4*k+1], v[4*k+2], v[4*k+3]);
        }
    }
    __syncthreads();

    // ---- T1 read (b32, <=2-way): t'[1:0]=e[1:0], t'[3:2]=e[11:10], t'[7:4]=e[9:6], j=e[5:2]
    //      u = j + 16*(t>>4) + 256*((t>>2)&3) -> addr = 4*(17*(t>>4) + 274*((t>>2)&3)) + (t&3) + 4j
    {
        const int rb = 4 * (17 * (t >> 4) + 274 * ((t >> 2) & 3)) + (t & 3);
#pragma unroll
        for (int j = 0; j < 16; ++j) v[j] = lds[rb + 4 * j];
    }

    fwht16(v);                                  // bits {2,3,4,5}
    __syncthreads();

    // ---- T2 write (b128): thread-major pad-20, addr = 20t + j ----
#pragma unroll
    for (int k = 0; k < 4; ++k) {
        *(float4*)&lds[20 * t + 4 * k] =
            make_float4(v[4*k], v[4*k+1], v[4*k+2], v[4*k+3]);
    }
    __syncthreads();

    // ---- T2 read (b32, <=2-way): t''[1:0]=e[1:0], t''[3:2]=e[11:10], t''[7:4]=e[5:2], j=e[9:6]
    //      source (t',j') = ((t''&15) + 16*j, t''>>4) -> addr = 20*(t''&15) + (t''>>4) + 320j
    {
        const int rb = 20 * (t & 15) + (t >> 4);
#pragma unroll
        for (int j = 0; j < 16; ++j) v[j] = lds[rb + 320 * j];
    }

    fwht16(v);                                  // bits {6,7,8,9}
    __syncthreads();

    // ---- T3 write (b32, <=2-way): e = (t&3) + 4*(t>>4) + 64j + 1024*((t>>2)&3)
    //      u = (t>>4) + 16j + 256*((t>>2)&3) -> addr = 4*((t>>4) + 274*((t>>2)&3)) + (t&3) + 68j
    {
        const int wb = 4 * ((t >> 4) + 274 * ((t >> 2) & 3)) + (t & 3);
#pragma unroll
        for (int j = 0; j < 16; ++j) lds[wb + 68 * j] = v[j];
    }
    __syncthreads();

    // ---- T3 read (b128): same address pattern as T1 write ----
    {
        const int gw = t + (t >> 4);
#pragma unroll
        for (int k = 0; k < 4; ++k) {
            float4 q = *(const float4*)&lds[4 * (gw + 274 * k)];
            v[4*k+0] = q.x; v[4*k+1] = q.y; v[4*k+2] = q.z; v[4*k+3] = q.w;
        }
    }

    // ---- Scale + store: unit-stride float4, same layout as load ----
    const float scale = 0.015625f;              // 1/sqrt(4096)
    float4* po = (float4*)(out + base);
#pragma unroll
    for (int k = 0; k < 4; ++k) {
        po[t + 256 * k] = make_float4(v[4*k] * scale, v[4*k+1] * scale,
                                      v[4*k+2] * scale, v[4*k+3] * scale);
    }
}

extern "C" void kernel_launch(void* const* d_in, const int* in_sizes, int n_in,
                              void* d_out, int out_size, void* d_ws, size_t ws_size,
                              hipStream_t stream) {
    const float* x = (const float*)d_in[0];
    float* out = (float*)d_out;
    const int rows = in_sizes[0] >> 12;         // elements / 4096
    fwht4096_kernel<<<rows, 256, 0, stream>>>(x, out);
}